// Round 1
// baseline (176.497 us; speedup 1.0000x reference)
//
#include <hip/hip_runtime.h>

#define N_NODES 8192
#define HIDDEN 256
#define OUT_DIM 16
#define CAP 128          // max neighbors stored; binomial max deg ~60 << 128
#define G_ROWS 16        // rows per block in the dense GEMM
#define NPB 8            // nodes per block in the sparse aggregate

// ---------------- K1: dense adjacency scan -> CSR + dinv; zero pooled -------
__global__ void k_build(const float* __restrict__ adj, float* __restrict__ dinv,
                        int* __restrict__ cnt, int* __restrict__ nbr,
                        float* __restrict__ pooled) {
    const int i = blockIdx.x;          // one row per block
    const int t = threadIdx.x;         // 256 threads
    __shared__ int scnt;
    if (t == 0) scnt = 0;
    __syncthreads();

    const uint4* row = (const uint4*)(adj + (size_t)i * N_NODES);
    #pragma unroll
    for (int c = 0; c < N_NODES / 4 / 256; ++c) {   // 8 iterations
        uint4 v = row[c * 256 + t];
        int base = (c * 256 + t) * 4;
        if (v.x | v.y | v.z | v.w) {   // adj values are exactly 0.0f or 1.0f
            if (v.x && base + 0 != i) { int p = atomicAdd(&scnt, 1); if (p < CAP) nbr[(size_t)i * CAP + p] = base + 0; }
            if (v.y && base + 1 != i) { int p = atomicAdd(&scnt, 1); if (p < CAP) nbr[(size_t)i * CAP + p] = base + 1; }
            if (v.z && base + 2 != i) { int p = atomicAdd(&scnt, 1); if (p < CAP) nbr[(size_t)i * CAP + p] = base + 2; }
            if (v.w && base + 3 != i) { int p = atomicAdd(&scnt, 1); if (p < CAP) nbr[(size_t)i * CAP + p] = base + 3; }
        }
    }
    __syncthreads();
    if (t == 0) {
        int c = scnt < CAP ? scnt : CAP;
        cnt[i] = c;
        dinv[i] = rsqrtf((float)(scnt + 1));   // +1 self loop; deg >= 1 always
    }
    if (i == 0 && t < HIDDEN) pooled[t] = 0.0f;
}

// ---------------- K2: s_i = dinv_i * (dinv_i + sum_{j in nbr} dinv_j) -------
__global__ void k_srow(const float* __restrict__ dinv, const int* __restrict__ cnt,
                       const int* __restrict__ nbr, float* __restrict__ s) {
    const int i = blockIdx.x;
    const int lane = threadIdx.x;      // 64 threads = 1 wave
    const float di = dinv[i];
    const int c = cnt[i];
    float p = 0.0f;
    for (int k = lane; k < c; k += 64) p += dinv[nbr[(size_t)i * CAP + k]];
    #pragma unroll
    for (int off = 32; off > 0; off >>= 1) p += __shfl_down(p, off);
    if (lane == 0) s[i] = di * (di + p);
}

// ---------------- K3: g = relu(s (x) W1 + b1) @ W2  ([8192,256]) ------------
__global__ void k_gemm(const float* __restrict__ s, const float* __restrict__ W1,
                       const float* __restrict__ b1, const float* __restrict__ W2,
                       float* __restrict__ g) {
    const int t = threadIdx.x;                 // 256 threads: output column
    const int row0 = blockIdx.x * G_ROWS;
    __shared__ float hT[HIDDEN][G_ROWS];       // k-major: 16 KB
    const float w1 = W1[t];
    const float bb = b1[t];
    for (int r = 0; r < G_ROWS; ++r) {
        hT[t][r] = fmaxf(s[row0 + r] * w1 + bb, 0.0f);
    }
    __syncthreads();

    float acc[G_ROWS];
    #pragma unroll
    for (int r = 0; r < G_ROWS; ++r) acc[r] = 0.0f;

    for (int k = 0; k < HIDDEN; ++k) {
        const float w2 = W2[k * HIDDEN + t];            // coalesced, L2-hot
        const float4 h0 = *(const float4*)&hT[k][0];    // wave-uniform broadcast
        const float4 h1 = *(const float4*)&hT[k][4];
        const float4 h2 = *(const float4*)&hT[k][8];
        const float4 h3 = *(const float4*)&hT[k][12];
        acc[0]  += h0.x * w2;  acc[1]  += h0.y * w2;  acc[2]  += h0.z * w2;  acc[3]  += h0.w * w2;
        acc[4]  += h1.x * w2;  acc[5]  += h1.y * w2;  acc[6]  += h1.z * w2;  acc[7]  += h1.w * w2;
        acc[8]  += h2.x * w2;  acc[9]  += h2.y * w2;  acc[10] += h2.z * w2;  acc[11] += h2.w * w2;
        acc[12] += h3.x * w2;  acc[13] += h3.y * w2;  acc[14] += h3.z * w2;  acc[15] += h3.w * w2;
    }
    #pragma unroll
    for (int r = 0; r < G_ROWS; ++r)
        g[(size_t)(row0 + r) * HIDDEN + t] = acc[r];
}

// ---------------- K4: h2 = relu(Nmat @ g + b2); pooled += sum rows ----------
__global__ void k_aggpool(const float* __restrict__ g, const float* __restrict__ dinv,
                          const int* __restrict__ cnt, const int* __restrict__ nbr,
                          const float* __restrict__ b2, float* __restrict__ pooled) {
    const int t = threadIdx.x;                 // column
    const int i0 = blockIdx.x * NPB;
    const float b = b2[t];
    float pool = 0.0f;
    for (int n = 0; n < NPB; ++n) {
        const int i = i0 + n;
        const float di = dinv[i];
        float val = di * g[(size_t)i * HIDDEN + t];     // self loop term
        const int c = cnt[i];
        const int* nb = nbr + (size_t)i * CAP;
        for (int k = 0; k < c; ++k) {
            const int j = nb[k];                        // wave-uniform
            val += dinv[j] * g[(size_t)j * HIDDEN + t]; // coalesced 1KB row, L2/L3-hot
        }
        val *= di;
        pool += fmaxf(val + b, 0.0f);
    }
    atomicAdd(&pooled[t], pool);
}

// ---------------- K5: out = pooled @ Wfc + bfc ------------------------------
__global__ void k_fc(const float* __restrict__ pooled, const float* __restrict__ Wfc,
                     const float* __restrict__ bfc, float* __restrict__ out) {
    const int t = threadIdx.x;      // 256
    const int o = t & 15;
    const int kg = t >> 4;
    float p = 0.0f;
    for (int k = kg; k < HIDDEN; k += 16) p += pooled[k] * Wfc[k * OUT_DIM + o];
    __shared__ float red[256];
    red[t] = p;
    __syncthreads();
    if (t < OUT_DIM) {
        float sum = bfc[t];
        #pragma unroll
        for (int q = 0; q < 16; ++q) sum += red[q * 16 + t];
        out[t] = sum;
    }
}

extern "C" void kernel_launch(void* const* d_in, const int* in_sizes, int n_in,
                              void* d_out, int out_size, void* d_ws, size_t ws_size,
                              hipStream_t stream) {
    const float* adj = (const float*)d_in[0];
    const float* W1  = (const float*)d_in[1];
    const float* b1  = (const float*)d_in[2];
    const float* W2  = (const float*)d_in[3];
    const float* b2  = (const float*)d_in[4];
    const float* Wfc = (const float*)d_in[5];
    const float* bfc = (const float*)d_in[6];
    float* out = (float*)d_out;

    // workspace layout (needs 16 MiB)
    char* ws = (char*)d_ws;
    float* dinv   = (float*)ws;                         // 8192 f
    float* s      = dinv + N_NODES;                     // 8192 f
    int*   cnt    = (int*)(s + N_NODES);                // 8192 i
    float* pooled = (float*)(cnt + N_NODES);            // 256 f
    int*   nbr    = (int*)(ws + (1 << 20));             // 8192*CAP i = 4 MiB
    float* g      = (float*)(ws + (8 << 20));           // 8192*256 f = 8 MiB

    k_build  <<<N_NODES, 256, 0, stream>>>(adj, dinv, cnt, nbr, pooled);
    k_srow   <<<N_NODES, 64,  0, stream>>>(dinv, cnt, nbr, s);
    k_gemm   <<<N_NODES / G_ROWS, 256, 0, stream>>>(s, W1, b1, W2, g);
    k_aggpool<<<N_NODES / NPB, 256, 0, stream>>>(g, dinv, cnt, nbr, b2, pooled);
    k_fc     <<<1, 256, 0, stream>>>(pooled, Wfc, bfc, out);
}

// Round 2
// 80.875 us; speedup vs baseline: 2.1823x; 2.1823x over previous
//
#include <hip/hip_runtime.h>

#define N_NODES 8192
#define HIDDEN 256
#define OUT_DIM 16
#define CAP 128          // max neighbors stored; binomial max deg ~60 << 128
#define G_ROWS 16        // rows per block in the slow dense GEMM
#define NPB 8            // nodes per block in slow sparse aggregate (P rows = 1024)
#define PROWS 1024

// ---------------- K_v: v = relu(W1) @ W2 ; flag = (b1 == 0 everywhere) ------
__global__ void k_v(const float* __restrict__ W1, const float* __restrict__ b1,
                    const float* __restrict__ W2, float* __restrict__ v,
                    int* __restrict__ flag) {
    const int c = threadIdx.x;                 // 256
    __shared__ float r[HIDDEN];
    __shared__ int nz;
    if (c == 0) nz = 0;
    __syncthreads();
    r[c] = fmaxf(W1[c], 0.0f);
    if (b1[c] != 0.0f) atomicOr(&nz, 1);
    __syncthreads();
    float acc = 0.0f;
    for (int k = 0; k < HIDDEN; ++k) acc += r[k] * W2[k * HIDDEN + c];  // coalesced
    v[c] = acc;
    if (c == 0) *flag = (nz == 0) ? 1 : 0;
}

// ---------------- K1: dense adjacency scan -> CSR + dinv --------------------
__global__ void k_build(const float* __restrict__ adj, float* __restrict__ dinv,
                        int* __restrict__ cnt, int* __restrict__ nbr) {
    const int i = blockIdx.x;          // one row per block
    const int t = threadIdx.x;         // 256 threads
    __shared__ int scnt;
    if (t == 0) scnt = 0;
    __syncthreads();

    const uint4* row = (const uint4*)(adj + (size_t)i * N_NODES);
    #pragma unroll
    for (int c = 0; c < N_NODES / 4 / 256; ++c) {   // 8 iterations
        uint4 v = row[c * 256 + t];
        int base = (c * 256 + t) * 4;
        if (v.x | v.y | v.z | v.w) {   // adj values are exactly 0.0f or 1.0f
            if (v.x && base + 0 != i) { int p = atomicAdd(&scnt, 1); if (p < CAP) nbr[(size_t)i * CAP + p] = base + 0; }
            if (v.y && base + 1 != i) { int p = atomicAdd(&scnt, 1); if (p < CAP) nbr[(size_t)i * CAP + p] = base + 1; }
            if (v.z && base + 2 != i) { int p = atomicAdd(&scnt, 1); if (p < CAP) nbr[(size_t)i * CAP + p] = base + 2; }
            if (v.w && base + 3 != i) { int p = atomicAdd(&scnt, 1); if (p < CAP) nbr[(size_t)i * CAP + p] = base + 3; }
        }
    }
    __syncthreads();
    if (t == 0) {
        int c = scnt < CAP ? scnt : CAP;
        cnt[i] = c;
        dinv[i] = rsqrtf((float)(scnt + 1));   // +1 self loop
    }
}

// ---------------- K2: s_i = di*(di + sum dinv_j); tt_i = di*s_i -------------
__global__ void k_srow(const float* __restrict__ dinv, const int* __restrict__ cnt,
                       const int* __restrict__ nbr, float* __restrict__ s,
                       float* __restrict__ tt) {
    const int w = threadIdx.x >> 6;    // wave 0..3, one node per wave
    const int lane = threadIdx.x & 63;
    const int i = blockIdx.x * 4 + w;
    const float di = dinv[i];
    const int c = cnt[i];
    float p = 0.0f;
    for (int k = lane; k < c; k += 64) p += dinv[nbr[(size_t)i * CAP + k]];
    #pragma unroll
    for (int off = 32; off > 0; off >>= 1) p += __shfl_down(p, off);
    if (lane == 0) { const float si = di * (di + p); s[i] = si; tt[i] = di * si; }
}

// ---------------- K3: q_i = di*(di*s_i + sum tt_j)  (q = Nmat @ s) ----------
__global__ void k_q(const float* __restrict__ dinv, const float* __restrict__ s,
                    const float* __restrict__ tt, const int* __restrict__ cnt,
                    const int* __restrict__ nbr, float* __restrict__ q) {
    const int w = threadIdx.x >> 6;
    const int lane = threadIdx.x & 63;
    const int i = blockIdx.x * 4 + w;
    const float di = dinv[i];
    const int c = cnt[i];
    float p = 0.0f;
    for (int k = lane; k < c; k += 64) p += tt[nbr[(size_t)i * CAP + k]];
    #pragma unroll
    for (int off = 32; off > 0; off >>= 1) p += __shfl_down(p, off);
    if (lane == 0) q[i] = di * (di * s[i] + p);
}

// ---------------- SLOW K4: g = relu(s (x) W1 + b1) @ W2  (predicated) -------
__global__ void k_gemm(const float* __restrict__ s, const float* __restrict__ W1,
                       const float* __restrict__ b1, const float* __restrict__ W2,
                       const int* __restrict__ flag, float* __restrict__ g) {
    if (*flag) return;                         // fast path active: no-op
    const int t = threadIdx.x;
    const int row0 = blockIdx.x * G_ROWS;
    __shared__ float hT[HIDDEN][G_ROWS];
    const float w1 = W1[t];
    const float bb = b1[t];
    for (int r = 0; r < G_ROWS; ++r)
        hT[t][r] = fmaxf(s[row0 + r] * w1 + bb, 0.0f);
    __syncthreads();

    float acc[G_ROWS];
    #pragma unroll
    for (int r = 0; r < G_ROWS; ++r) acc[r] = 0.0f;
    for (int k = 0; k < HIDDEN; ++k) {
        const float w2 = W2[k * HIDDEN + t];
        const float4 h0 = *(const float4*)&hT[k][0];
        const float4 h1 = *(const float4*)&hT[k][4];
        const float4 h2 = *(const float4*)&hT[k][8];
        const float4 h3 = *(const float4*)&hT[k][12];
        acc[0]  += h0.x * w2;  acc[1]  += h0.y * w2;  acc[2]  += h0.z * w2;  acc[3]  += h0.w * w2;
        acc[4]  += h1.x * w2;  acc[5]  += h1.y * w2;  acc[6]  += h1.z * w2;  acc[7]  += h1.w * w2;
        acc[8]  += h2.x * w2;  acc[9]  += h2.y * w2;  acc[10] += h2.z * w2;  acc[11] += h2.w * w2;
        acc[12] += h3.x * w2;  acc[13] += h3.y * w2;  acc[14] += h3.z * w2;  acc[15] += h3.w * w2;
    }
    #pragma unroll
    for (int r = 0; r < G_ROWS; ++r)
        g[(size_t)(row0 + r) * HIDDEN + t] = acc[r];
}

// ---------------- SLOW K5: partial pooled rows from sparse aggregate --------
__global__ void k_aggslow(const float* __restrict__ g, const float* __restrict__ dinv,
                          const int* __restrict__ cnt, const int* __restrict__ nbr,
                          const float* __restrict__ b2, const int* __restrict__ flag,
                          float* __restrict__ P) {
    const int t = threadIdx.x;
    if (*flag) { P[(size_t)blockIdx.x * HIDDEN + t] = 0.0f; return; }  // zero my row
    const int i0 = blockIdx.x * NPB;
    const float b = b2[t];
    float pool = 0.0f;
    for (int n = 0; n < NPB; ++n) {
        const int i = i0 + n;
        const float di = dinv[i];
        float val = di * g[(size_t)i * HIDDEN + t];
        const int c = cnt[i];
        const int* nb = nbr + (size_t)i * CAP;
        for (int k = 0; k < c; ++k) {
            const int j = nb[k];
            val += dinv[j] * g[(size_t)j * HIDDEN + t];
        }
        val *= di;
        pool += fmaxf(val + b, 0.0f);
    }
    P[(size_t)blockIdx.x * HIDDEN + t] = pool;
}

// ---------------- FAST K6: pooled partials = sum relu(q_i*v + b2) -----------
__global__ void k_poolfast(const float* __restrict__ q, const float* __restrict__ v,
                           const float* __restrict__ b2, const int* __restrict__ flag,
                           float* __restrict__ P) {
    if (!*flag) return;                        // slow path owns P
    const int t = threadIdx.x;
    const float vc = v[t];
    const float bc = b2[t];
    const int i0 = blockIdx.x * (N_NODES / 64);   // 64 blocks x 128 nodes
    float p = 0.0f;
    for (int n = 0; n < N_NODES / 64; ++n)
        p += fmaxf(q[i0 + n] * vc + bc, 0.0f);     // q load is wave-uniform bcast
    P[(size_t)blockIdx.x * HIDDEN + t] = p;        // overwrites slow-path zeros
}

// ---------------- K7: reduce P[1024] -> Q[32] -------------------------------
__global__ void k_reduce(const float* __restrict__ P, float* __restrict__ Q) {
    const int t = threadIdx.x;
    const int b0 = blockIdx.x * 32;
    float acc = 0.0f;
    #pragma unroll
    for (int b = 0; b < 32; ++b) acc += P[(size_t)(b0 + b) * HIDDEN + t];
    Q[(size_t)blockIdx.x * HIDDEN + t] = acc;
}

// ---------------- K8: pooled = sum Q; out = pooled @ Wfc + bfc --------------
__global__ void k_fc(const float* __restrict__ Q, const float* __restrict__ Wfc,
                     const float* __restrict__ bfc, float* __restrict__ out) {
    const int t = threadIdx.x;      // 256
    float ps = 0.0f;
    #pragma unroll
    for (int qq = 0; qq < 32; ++qq) ps += Q[(size_t)qq * HIDDEN + t];
    __shared__ float pooled[HIDDEN];
    pooled[t] = ps;
    __syncthreads();
    const int o = t & 15;
    const int kg = t >> 4;
    float pr = 0.0f;
    for (int k = kg; k < HIDDEN; k += 16) pr += pooled[k] * Wfc[k * OUT_DIM + o];
    __shared__ float red[256];
    red[t] = pr;
    __syncthreads();
    if (t < OUT_DIM) {
        float sum = bfc[t];
        #pragma unroll
        for (int g = 0; g < 16; ++g) sum += red[g * 16 + t];
        out[t] = sum;
    }
}

extern "C" void kernel_launch(void* const* d_in, const int* in_sizes, int n_in,
                              void* d_out, int out_size, void* d_ws, size_t ws_size,
                              hipStream_t stream) {
    const float* adj = (const float*)d_in[0];
    const float* W1  = (const float*)d_in[1];
    const float* b1  = (const float*)d_in[2];
    const float* W2  = (const float*)d_in[3];
    const float* b2  = (const float*)d_in[4];
    const float* Wfc = (const float*)d_in[5];
    const float* bfc = (const float*)d_in[6];
    float* out = (float*)d_out;

    // workspace layout (16 MiB used)
    char* ws = (char*)d_ws;
    float* dinv = (float*)(ws + 0);                 // 32 KB
    float* s    = (float*)(ws + (32 << 10));        // 32 KB
    float* tt   = (float*)(ws + (64 << 10));        // 32 KB
    float* q    = (float*)(ws + (96 << 10));        // 32 KB
    int*   cnt  = (int*)  (ws + (128 << 10));       // 32 KB
    float* v    = (float*)(ws + (160 << 10));       // 1 KB
    int*   flag = (int*)  (ws + (164 << 10));       // 4 B
    float* Q    = (float*)(ws + (256 << 10));       // 32 KB
    float* P    = (float*)(ws + (1 << 20));         // 1 MB  (1024 x 256)
    int*   nbr  = (int*)  (ws + (2 << 20));         // 4 MB
    float* g    = (float*)(ws + (8 << 20));         // 8 MB

    k_v       <<<1, 256, 0, stream>>>(W1, b1, W2, v, flag);
    k_build   <<<N_NODES, 256, 0, stream>>>(adj, dinv, cnt, nbr);
    k_srow    <<<N_NODES / 4, 256, 0, stream>>>(dinv, cnt, nbr, s, tt);
    k_q       <<<N_NODES / 4, 256, 0, stream>>>(dinv, s, tt, cnt, nbr, q);
    k_gemm    <<<N_NODES / G_ROWS, 256, 0, stream>>>(s, W1, b1, W2, flag, g);
    k_aggslow <<<PROWS, 256, 0, stream>>>(g, dinv, cnt, nbr, b2, flag, P);
    k_poolfast<<<64, 256, 0, stream>>>(q, v, b2, flag, P);
    k_reduce  <<<32, 256, 0, stream>>>(P, Q);
    k_fc      <<<1, 256, 0, stream>>>(Q, Wfc, bfc, out);
}

// Round 4
// 80.787 us; speedup vs baseline: 2.1847x; 1.0011x over previous
//
#include <hip/hip_runtime.h>

#define N_NODES 8192
#define HIDDEN 256
#define OUT_DIM 16
#define CAP 128          // max neighbors stored; binomial max deg ~60 << 128
#define G_ROWS 16        // rows per block in the slow dense GEMM
#define PBLK 512         // pool-partial blocks (both paths write P[PBLK][HIDDEN])
#define NPB (N_NODES / PBLK)   // 16 nodes per pool block

// ---------------- K0: zero cnt; v = relu(W1)@W2; flag = (b1==0) -------------
__global__ void k_init(const float* __restrict__ W1, const float* __restrict__ b1,
                       const float* __restrict__ W2, int* __restrict__ cnt,
                       float* __restrict__ v, int* __restrict__ flag) {
    const int t = threadIdx.x;         // 256
    const int bid = blockIdx.x;        // 33
    if (bid < 32) {
        cnt[bid * 256 + t] = 0;
        return;
    }
    // block 32: v and flag (independent of adj)
    float acc = 0.0f;
    for (int k = 0; k < HIDDEN; ++k)
        acc += fmaxf(W1[k], 0.0f) * W2[(size_t)k * HIDDEN + t];   // coalesced
    v[t] = acc;
    __shared__ int nz;
    if (t == 0) nz = 0;
    __syncthreads();
    if (b1[t] != 0.0f) atomicOr(&nz, 1);
    __syncthreads();
    if (t == 0) *flag = (nz == 0) ? 1 : 0;
}

// ---------------- K1: upper-triangle scan (adj symmetric) -> CSR ------------
__device__ __forceinline__ void add_edge(int i, int j, int* cnt, int* nbr) {
    int p = atomicAdd(&cnt[i], 1);
    if (p < CAP) nbr[(size_t)i * CAP + p] = j;
    int q = atomicAdd(&cnt[j], 1);
    if (q < CAP) nbr[(size_t)j * CAP + q] = i;
}

__device__ __forceinline__ void scan_row(const float* __restrict__ adj, int i,
                                         int t, int* cnt, int* nbr) {
    const uint4* row4 = (const uint4*)(adj + (size_t)i * N_NODES);
    const int k0 = (i + 1) >> 2;       // first uint4 that can contain cols > i
    for (int k = k0 + t; k < N_NODES / 4; k += 256) {
        uint4 vv = row4[k];
        if (vv.x | vv.y | vv.z | vv.w) {   // entries are exactly 0.0f or 1.0f
            int base = k * 4;
            if (vv.x && base + 0 > i) add_edge(i, base + 0, cnt, nbr);
            if (vv.y && base + 1 > i) add_edge(i, base + 1, cnt, nbr);
            if (vv.z && base + 2 > i) add_edge(i, base + 2, cnt, nbr);
            if (vv.w && base + 3 > i) add_edge(i, base + 3, cnt, nbr);
        }
    }
}

__global__ void k_scan(const float* __restrict__ adj, int* __restrict__ cnt,
                       int* __restrict__ nbr) {
    const int t = threadIdx.x;             // 256
    const int ia = blockIdx.x;             // 0..4095
    const int ib = N_NODES - 1 - ia;       // 8191..4096  (span ia elems)
    scan_row(adj, ia, t, cnt, nbr);        // span 8191-ia elems
    scan_row(adj, ib, t, cnt, nbr);        // combined ~8191 per block
}

// ---------------- K2: s_i = di*(di + sum dinv_j); tt_i = di*s_i; dinv -------
__global__ void k_srow(const int* __restrict__ cnt, const int* __restrict__ nbr,
                       float* __restrict__ s, float* __restrict__ tt,
                       float* __restrict__ dinv) {
    const int w = threadIdx.x >> 6;    // wave 0..3, one node per wave
    const int lane = threadIdx.x & 63;
    const int i = blockIdx.x * 4 + w;
    const int c0 = cnt[i];
    const int c = c0 < CAP ? c0 : CAP;
    const float di = rsqrtf((float)(c0 + 1));   // +1 self loop
    float p = 0.0f;
    for (int k = lane; k < c; k += 64)
        p += rsqrtf((float)(cnt[nbr[(size_t)i * CAP + k]] + 1));
    #pragma unroll
    for (int off = 32; off > 0; off >>= 1) p += __shfl_down(p, off);
    if (lane == 0) {
        const float si = di * (di + p);
        s[i] = si; tt[i] = di * si; dinv[i] = di;
    }
}

// ---------------- SLOW K3: g = relu(s (x) W1 + b1) @ W2  (predicated) -------
__global__ void k_gemm(const float* __restrict__ s, const float* __restrict__ W1,
                       const float* __restrict__ b1, const float* __restrict__ W2,
                       const int* __restrict__ flag, float* __restrict__ g) {
    if (*flag) return;                         // fast path active: no-op
    const int t = threadIdx.x;
    const int row0 = blockIdx.x * G_ROWS;
    __shared__ float hT[HIDDEN][G_ROWS];
    const float w1 = W1[t];
    const float bb = b1[t];
    for (int r = 0; r < G_ROWS; ++r)
        hT[t][r] = fmaxf(s[row0 + r] * w1 + bb, 0.0f);
    __syncthreads();

    float acc[G_ROWS];
    #pragma unroll
    for (int r = 0; r < G_ROWS; ++r) acc[r] = 0.0f;
    for (int k = 0; k < HIDDEN; ++k) {
        const float w2 = W2[(size_t)k * HIDDEN + t];
        const float4 h0 = *(const float4*)&hT[k][0];
        const float4 h1 = *(const float4*)&hT[k][4];
        const float4 h2 = *(const float4*)&hT[k][8];
        const float4 h3 = *(const float4*)&hT[k][12];
        acc[0]  += h0.x * w2;  acc[1]  += h0.y * w2;  acc[2]  += h0.z * w2;  acc[3]  += h0.w * w2;
        acc[4]  += h1.x * w2;  acc[5]  += h1.y * w2;  acc[6]  += h1.z * w2;  acc[7]  += h1.w * w2;
        acc[8]  += h2.x * w2;  acc[9]  += h2.y * w2;  acc[10] += h2.z * w2;  acc[11] += h2.w * w2;
        acc[12] += h3.x * w2;  acc[13] += h3.y * w2;  acc[14] += h3.z * w2;  acc[15] += h3.w * w2;
    }
    #pragma unroll
    for (int r = 0; r < G_ROWS; ++r)
        g[(size_t)(row0 + r) * HIDDEN + t] = acc[r];
}

// ---------------- K4: pool partials, both paths -> P[PBLK][HIDDEN] ----------
__global__ void k_pool(const int* __restrict__ cnt, const int* __restrict__ nbr,
                       const float* __restrict__ s, const float* __restrict__ tt,
                       const float* __restrict__ dinv, const float* __restrict__ g,
                       const float* __restrict__ v, const float* __restrict__ b2,
                       const int* __restrict__ flag, float* __restrict__ P) {
    const int t = threadIdx.x;
    const int bid = blockIdx.x;            // 512
    if (*flag) {
        // FAST: q_i = di*(di*s_i + sum tt_j); pp = sum_n relu(q_n*v_t + b2_t)
        __shared__ float qsh[NPB];
        const int w = t >> 6, lane = t & 63;
        #pragma unroll
        for (int n = 0; n < NPB / 4; ++n) {        // 4 nodes per wave
            const int i = bid * NPB + w * (NPB / 4) + n;
            const int c0 = cnt[i];
            const int c = c0 < CAP ? c0 : CAP;
            const float di = rsqrtf((float)(c0 + 1));
            float p = 0.0f;
            for (int k = lane; k < c; k += 64) p += tt[nbr[(size_t)i * CAP + k]];
            #pragma unroll
            for (int off = 32; off > 0; off >>= 1) p += __shfl_down(p, off);
            if (lane == 0) qsh[w * (NPB / 4) + n] = di * (di * s[i] + p);
        }
        __syncthreads();
        const float vc = v[t], bc = b2[t];
        float pp = 0.0f;
        #pragma unroll
        for (int n = 0; n < NPB; ++n) pp += fmaxf(qsh[n] * vc + bc, 0.0f);
        P[(size_t)bid * HIDDEN + t] = pp;
    } else {
        // SLOW: aggregate g + bias + relu + partial pool
        const float bb2 = b2[t];
        float pool = 0.0f;
        for (int n = 0; n < NPB; ++n) {
            const int i = bid * NPB + n;
            const float di = dinv[i];
            float val = di * g[(size_t)i * HIDDEN + t];
            const int c0 = cnt[i];
            const int c = c0 < CAP ? c0 : CAP;
            const int* nb = nbr + (size_t)i * CAP;
            for (int k = 0; k < c; ++k) {
                const int j = nb[k];
                val += dinv[j] * g[(size_t)j * HIDDEN + t];
            }
            val *= di;
            pool += fmaxf(val + bb2, 0.0f);
        }
        P[(size_t)bid * HIDDEN + t] = pool;
    }
}

// ---------------- K5: pooled = sum P; out = pooled @ Wfc + bfc --------------
__global__ void k_finish(const float* __restrict__ P, const float* __restrict__ Wfc,
                         const float* __restrict__ bfc, float* __restrict__ out) {
    const int t = threadIdx.x;      // 256
    float a0 = 0.f, a1 = 0.f, a2 = 0.f, a3 = 0.f;
    #pragma unroll 8
    for (int r = 0; r < PBLK; r += 4) {
        a0 += P[(size_t)(r + 0) * HIDDEN + t];
        a1 += P[(size_t)(r + 1) * HIDDEN + t];
        a2 += P[(size_t)(r + 2) * HIDDEN + t];
        a3 += P[(size_t)(r + 3) * HIDDEN + t];
    }
    __shared__ float pooled[HIDDEN];
    pooled[t] = (a0 + a1) + (a2 + a3);
    __syncthreads();
    const int o = t & 15, kg = t >> 4;
    float pr = 0.0f;
    for (int k = kg; k < HIDDEN; k += 16) pr += pooled[k] * Wfc[k * OUT_DIM + o];
    __shared__ float red[256];
    red[t] = pr;
    __syncthreads();
    if (t < OUT_DIM) {
        float sum = bfc[t];
        #pragma unroll
        for (int gg = 0; gg < 16; ++gg) sum += red[gg * 16 + t];
        out[t] = sum;
    }
}

extern "C" void kernel_launch(void* const* d_in, const int* in_sizes, int n_in,
                              void* d_out, int out_size, void* d_ws, size_t ws_size,
                              hipStream_t stream) {
    const float* adj = (const float*)d_in[0];
    const float* W1  = (const float*)d_in[1];
    const float* b1  = (const float*)d_in[2];
    const float* W2  = (const float*)d_in[3];
    const float* b2  = (const float*)d_in[4];
    const float* Wfc = (const float*)d_in[5];
    const float* bfc = (const float*)d_in[6];
    float* out = (float*)d_out;

    // workspace layout (16 MiB used)
    char* ws = (char*)d_ws;
    int*   cnt  = (int*)  (ws + 0);                 // 32 KB
    float* s    = (float*)(ws + (32 << 10));        // 32 KB
    float* tt   = (float*)(ws + (64 << 10));        // 32 KB
    float* dinv = (float*)(ws + (96 << 10));        // 32 KB (slow path)
    float* v    = (float*)(ws + (128 << 10));       // 1 KB
    int*   flag = (int*)  (ws + (132 << 10));       // 4 B
    float* P    = (float*)(ws + (256 << 10));       // 512 KB (512 x 256)
    int*   nbr  = (int*)  (ws + (2 << 20));         // 4 MB
    float* g    = (float*)(ws + (8 << 20));         // 8 MB (slow path only)

    k_init  <<<33, 256, 0, stream>>>(W1, b1, W2, cnt, v, flag);
    k_scan  <<<N_NODES / 2, 256, 0, stream>>>(adj, cnt, nbr);
    k_srow  <<<N_NODES / 4, 256, 0, stream>>>(cnt, nbr, s, tt, dinv);
    k_gemm  <<<N_NODES / G_ROWS, 256, 0, stream>>>(s, W1, b1, W2, flag, g);
    k_pool  <<<PBLK, 256, 0, stream>>>(cnt, nbr, s, tt, dinv, g, v, b2, flag, P);
    k_finish<<<1, 256, 0, stream>>>(P, Wfc, bfc, out);
}